// Round 1
// 90.369 us; speedup vs baseline: 1.0096x; 1.0096x over previous
//
#include <hip/hip_runtime.h>

#define HH 256
#define LPITCH 52                    // LDS dwords per row (48 used + 4 pad -> bank spread)
#define LROWS  69                    // rows staged per block: [G0, G0+68]

__device__ __forceinline__ unsigned sad8(unsigned a, unsigned b, unsigned c) {
  unsigned d;
  asm("v_sad_u8 %0, %1, %2, %3" : "=v"(d) : "v"(a), "v"(b), "v"(c));
  return d;
}
__device__ __forceinline__ unsigned sad32(unsigned a, unsigned b, unsigned c) {
  unsigned d;
  asm("v_sad_u32 %0, %1, %2, %3" : "=v"(d) : "v"(a), "v"(b), "v"(c));
  return d;
}
__device__ __forceinline__ unsigned mad24(unsigned a, unsigned b, unsigned c) {
  unsigned d;
  asm("v_mad_u32_u24 %0, %1, %2, %3" : "=v"(d) : "v"(a), "v"(b), "v"(c));
  return d;
}
__device__ __forceinline__ unsigned q8(float x) { return (unsigned)(x * 255.0f + 0.5f); }
__device__ __forceinline__ unsigned eld(uint4 v, int k) {
  return k == 0 ? v.x : k == 1 ? v.y : k == 2 ? v.z : v.w;
}
#define ELD(ARR, M) eld(ARR[(M) >> 2], (M) & 3)

// window dword M in [0,23] <-> pixel col xp0 - 3 + M; pair (P,J): M = P+J+8; cen: M = P+8
// LDS col 0 == pixel col bx*32 - 8; thread reads dwords [8*lx, 8*lx+24)
#define LOADR(S, R)                                                         \
  { const uint4* q0_ = (const uint4*)&lds[0][R][8 * lx];                    \
    const uint4* q1_ = (const uint4*)&lds[1][R][8 * lx];                    \
    S##0[0]=q0_[0]; S##0[1]=q0_[1]; S##0[2]=q0_[2];                         \
    S##0[3]=q0_[3]; S##0[4]=q0_[4]; S##0[5]=q0_[5];                         \
    S##1[0]=q1_[0]; S##1[1]=q1_[1]; S##1[2]=q1_[2];                         \
    S##1[3]=q1_[3]; S##1[4]=q1_[4]; S##1[5]=q1_[5]; }

#define PF(S, P, J)                                                         \
  { unsigned so_ = sad8(cen0[P], ELD(S##0, (P)+(J)+8), zr);                 \
    unsigned ss_ = sad8(cen1[P], ELD(S##1, (P)+(J)+8), zr);                 \
    acc = sad32(so_, ss_, acc); }
#define PM(S, P, J)                                                         \
  { unsigned so_ = sad8(cen0[P], ELD(S##0, (P)+(J)+8), zr);                 \
    unsigned ss_ = sad8(cen1[P], ELD(S##1, (P)+(J)+8), zr);                 \
    unsigned d_  = sad32(so_, ss_, zr);                                     \
    unsigned w2_ = cenv[P] + (ym & xok[(P)+(J)+8]);                         \
    acc = mad24(d_, w2_, acc); }

#define JF(S,J) PF(S,0,J) PF(S,1,J) PF(S,2,J) PF(S,3,J)                     \
                PF(S,4,J) PF(S,5,J) PF(S,6,J) PF(S,7,J)
#define JM(S,J) PM(S,0,J) PM(S,1,J) PM(S,2,J) PM(S,3,J)                     \
                PM(S,4,J) PM(S,5,J) PM(S,6,J) PM(S,7,J)
#define ROWF(S) JF(S,-5) JF(S,-4) JF(S,-3) JF(S,-2) JF(S,-1) JF(S,0)        \
                JF(S,1) JF(S,2) JF(S,3) JF(S,4) JF(S,5)
#define ROWM(S) JM(S,-5) JM(S,-4) JM(S,-3) JM(S,-2) JM(S,-1) JM(S,0)        \
                JM(S,1) JM(S,2) JM(S,3) JM(S,4) JM(S,5)

// Fused: pack fp32 RGB -> u8 RGB0 dwords into LDS per block, then sad main loop.
// No workspace, no intermediate global buffer.
__global__ __launch_bounds__(256, 2)
void contrast_fused(const float* __restrict__ orig, const float* __restrict__ sim,
                    float* __restrict__ out) {
  __shared__ unsigned lds[2][LROWS][LPITCH];   // 28704 B
  __shared__ float wsum[4];
  const int tid = threadIdx.x, lane = tid & 63, wv = tid >> 6;
  const int bx = blockIdx.x, by = blockIdx.y, b = blockIdx.z;
  const int lx = lane & 3, ly = lane >> 2;

  // ---- stage: pack the block's 2-image 69x48 pixel region into LDS ----
  // quad item: img in {0,1}, r in [0,69), q in [0,12) -> 4 packed dwords
  const int G0 = by * 64;
  const int c0base = bx * 32 - 8;
  #pragma unroll
  for (int i = 0; i < 7; ++i) {
    int idx = i * 256 + tid;                 // 0 .. 1791; 1656 real items
    if (idx < 2 * LROWS * 12) {
      int q   = idx % 12;
      int ri  = idx / 12;                    // 0..137
      int img = (ri >= LROWS) ? 1 : 0;
      int r   = ri - img * LROWS;            // 0..68
      int row = G0 + r;                      // pixel row; may exceed 255 (by=3)
      if (row > 255) row = 255;              // clamped values only read with weight 0
      int col = c0base + 4 * q;              // pixel col; may be <0 or >252
      if (col < 0) col = 0;
      if (col > 252) col = 252;
      const float* p = (img ? sim : orig) + (size_t)b * 3 * HH * HH + row * HH + col;
      float4 va = *(const float4*)(p);
      float4 vb = *(const float4*)(p + HH * HH);
      float4 vc = *(const float4*)(p + 2 * HH * HH);
      uint4 pk;
      pk.x = q8(va.x) | (q8(vb.x) << 8) | (q8(vc.x) << 16);
      pk.y = q8(va.y) | (q8(vb.y) << 8) | (q8(vc.y) << 16);
      pk.z = q8(va.z) | (q8(vb.z) << 8) | (q8(vc.z) << 16);
      pk.w = q8(va.w) | (q8(vb.w) << 8) | (q8(vc.w) << 16);
      *(uint4*)&lds[img][r][4 * q] = pk;
    }
  }
  __syncthreads();

  // ---- main loop (identical math to the two-kernel version, LDS-sourced) ----
  const int G   = G0 + wv * 16;
  const int y0  = G + ly - 5;               // output row p'_y
  const int xp0 = bx * 32 + 8 * lx - 5;     // output col p'_x for P=0
  const int rbase = wv * 16 + ly;           // LDS row of pixel row y0+5 (k=0)

  uint4 A0[6], A1[6], B0[6], B1[6];
  unsigned cen0[8], cen1[8];
  unsigned zr = 0, acc = 0;

  const bool fastw = (bx >= 1) && (bx <= 6) && (G >= 16) && (G <= 224);

  LOADR(A, rbase)                           // row k=0  (pixel row y0+5)
  LOADR(B, rbase + 1)                       // row k=1
  #pragma unroll
  for (int p = 0; p < 8; ++p) { cen0[p] = ELD(A0, p + 8); cen1[p] = ELD(A1, p + 8); }

  float ftot;
  if (fastw) {
    JF(A,1) JF(A,2) JF(A,3) JF(A,4) JF(A,5)          // k=0: j=1..5
    #pragma unroll 1
    for (int t = 0; t < 2; ++t) {
      LOADR(A, rbase + 2 * t + 2)                    // row 2t+2
      ROWF(B)                                        // row 2t+1
      LOADR(B, rbase + 2 * t + 3)                    // row 2t+3
      ROWF(A)                                        // row 2t+2
    }
    ROWF(B)                                          // row 5
    ftot = 2.0f * (float)acc;                        // exact: acc < 2^21
  } else {
    unsigned xok[24];
    #pragma unroll
    for (int m = 0; m < 24; ++m)
      xok[m] = ((unsigned)(xp0 + m - 8) < 246u) ? 1u : 0u;
    const unsigned ym0v = ((unsigned)y0 < 246u) ? 1u : 0u;
    unsigned cenv[8];
    #pragma unroll
    for (int p = 0; p < 8; ++p) cenv[p] = ym0v & xok[p + 8];

    unsigned ym = ym0v;                              // k=0 target row == center row
    JM(A,1) JM(A,2) JM(A,3) JM(A,4) JM(A,5)
    #pragma unroll 1
    for (int t = 0; t < 2; ++t) {
      LOADR(A, rbase + 2 * t + 2)
      ym = ((unsigned)(y0 + 2 * t + 1) < 246u) ? 1u : 0u;
      ROWM(B)
      LOADR(B, rbase + 2 * t + 3)
      ym = ((unsigned)(y0 + 2 * t + 2) < 246u) ? 1u : 0u;
      ROWM(A)
    }
    ym = ((unsigned)(y0 + 5) < 246u) ? 1u : 0u;
    ROWM(B)
    ftot = (float)acc;                               // exact: acc < 2^22
  }

  // ---- reduce: wave shuffle -> LDS -> one atomic per block ----
  #pragma unroll
  for (int off = 32; off > 0; off >>= 1)
    ftot += __shfl_down(ftot, off, 64);
  if (lane == 0) wsum[wv] = ftot;
  __syncthreads();
  if (tid == 0) {
    const float scale = (1.0f / 255.0f) / 116190720.0f;   // dequant + mean
    atomicAdd(out, (wsum[0] + wsum[1] + wsum[2] + wsum[3]) * scale);
  }
}

extern "C" void kernel_launch(void* const* d_in, const int* in_sizes, int n_in,
                              void* d_out, int out_size, void* d_ws, size_t ws_size,
                              hipStream_t stream) {
  (void)in_sizes; (void)n_in; (void)ws_size; (void)out_size; (void)d_ws;
  const float* orig = (const float*)d_in[0];
  const float* sim  = (const float*)d_in[1];
  float* out = (float*)d_out;

  hipMemsetAsync(out, 0, sizeof(float), stream);
  hipLaunchKernelGGL(contrast_fused, dim3(8, 4, 16), dim3(256), 0, stream, orig, sim, out);
}